// Round 3
// baseline (486.322 us; speedup 1.0000x reference)
//
#include <hip/hip_runtime.h>
#include <hip/hip_bf16.h>
#include <stdint.h>

// AFT-full, MI355X. Shapes: x[64,1024,512], W*[512,512], pos_bias[1024,1024].
//   q,k,v = x W^T + b ; out = sigmoid(q) * (eb@(e^k*v)) / (eb@e^k), eb=exp(pos_bias)
// Pipeline:
//   K0: eb = bf16(exp(pos_bias))                      [1024,1024]
//   K1: xb = bf16(x), Wb = bf16([Wq;Wk;Wv]) [1536][512]
//   P1: fused QKV GEMM (bf16 MFMA, fp32 acc, global_load_lds + slot-swizzle):
//        s   = bf16(sigmoid(q))  natural [b,j,d]
//        ekT = bf16(exp(k))      transposed [b][d][j]
//        vT  = bf16(v)           transposed [b][d][j]
//   K2: ekvT = ekT * vT elementwise (in-place over vT)
//   P2: per-batch GEMM C[i,d]: num=eb@ekv, den=eb@ek (dual acc, pure async
//       swizzled staging), epilogue out = s*num/den (fp32). XCD-chunked grid.
// Workspace: eb 2MiB@0, Wb 1.5MiB@2MiB, xb 64MiB@4MiB, s@68MiB, ekT@132MiB,
//            vT/ekvT@196MiB.

#define NSEQ 1024
#define DM   512

typedef __attribute__((ext_vector_type(8))) short bf16x8;
typedef __attribute__((ext_vector_type(4))) float f32x4;

static __device__ __forceinline__ float b2f(unsigned short u) {
    union { uint32_t i; float f; } c; c.i = ((uint32_t)u) << 16; return c.f;
}
// round-to-nearest-even fp32 -> bf16 (inputs finite)
static __device__ __forceinline__ unsigned short f2b(float f) {
    union { float f; uint32_t i; } c; c.f = f;
    uint32_t r = c.i + 0x7FFFu + ((c.i >> 16) & 1u);
    return (unsigned short)(r >> 16);
}

// async global->LDS, 16B per lane; lds dest = wave-uniform base + lane*16
static __device__ __forceinline__ void gl_lds16(const unsigned short* g, unsigned short* l) {
    __builtin_amdgcn_global_load_lds(
        (const __attribute__((address_space(1))) unsigned int*)(g),
        (__attribute__((address_space(3))) unsigned int*)(l), 16, 0, 0);
}

__global__ void k_eb(const float* __restrict__ pb, unsigned short* __restrict__ eb) {
    int i = blockIdx.x * 256 + threadIdx.x;           // one float4 per thread
    float4 v = reinterpret_cast<const float4*>(pb)[i];
    union { unsigned short u[4]; uint2 p; } o;
    o.u[0] = f2b(expf(v.x)); o.u[1] = f2b(expf(v.y));
    o.u[2] = f2b(expf(v.z)); o.u[3] = f2b(expf(v.w));
    reinterpret_cast<uint2*>(eb)[i] = o.p;
}

// fp32 -> bf16, 8 elements/thread
__global__ void k_cvt(const float* __restrict__ src, unsigned short* __restrict__ dst) {
    int i = blockIdx.x * 256 + threadIdx.x;
    const float4* p = reinterpret_cast<const float4*>(src) + (size_t)i * 2;
    float4 f0 = p[0], f1 = p[1];
    union { unsigned short u[8]; int4 v; } o;
    o.u[0]=f2b(f0.x); o.u[1]=f2b(f0.y); o.u[2]=f2b(f0.z); o.u[3]=f2b(f0.w);
    o.u[4]=f2b(f1.x); o.u[5]=f2b(f1.y); o.u[6]=f2b(f1.z); o.u[7]=f2b(f1.w);
    reinterpret_cast<int4*>(dst)[i] = o.v;
}

// ekv = ek * v elementwise (bf16), 8/thread, in-place over v
__global__ void k_ekv(const unsigned short* __restrict__ ekT,
                      unsigned short* __restrict__ vT) {
    int i = blockIdx.x * 256 + threadIdx.x;
    int4 e8 = reinterpret_cast<const int4*>(ekT)[i];
    int4 v8 = reinterpret_cast<const int4*>(vT)[i];
    union { unsigned short u[8]; int4 v; } pe, pv, po;
    pe.v = e8; pv.v = v8;
    #pragma unroll
    for (int j = 0; j < 8; ++j) po.u[j] = f2b(b2f(pe.u[j]) * b2f(pv.u[j]));
    reinterpret_cast<int4*>(vT)[i] = po.v;
}

// ---------------- P1: fused QKV projection ----------------
// 6144 blocks: XCD-swizzled; etile (12) fast, mtile (512) slow.
__launch_bounds__(256)
__global__ void k_qkv(const unsigned short* __restrict__ xb,
                      const unsigned short* __restrict__ Wb,
                      const float* __restrict__ bq, const float* __restrict__ bk,
                      const float* __restrict__ bv,
                      unsigned short* __restrict__ s_out,
                      unsigned short* __restrict__ ekT,
                      unsigned short* __restrict__ vT)
{
    __shared__ unsigned short smem[17408];            // As|Bs (16384) ; T overlay (17408)
    unsigned short* As = smem;                        // [128][64] linear, slot-swizzled
    unsigned short* Bs = smem + 128 * 64;

    const int bid = blockIdx.x;
    const int swz = (bid & 7) * 768 + (bid >> 3);     // bijective: 6144 % 8 == 0
    const int mtile = swz / 12, etile = swz % 12;
    const int brow = mtile * 128;                     // global m
    const int erow = etile * 128;                     // row in Wb [1536][512]
    const int sel  = etile >> 2;                      // 0=q 1=k 2=v
    const int ecol = (etile & 3) * 128;               // col within this W
    const float* bias = (sel == 0) ? bq : (sel == 1) ? bk : bv;

    const int tid = threadIdx.x;
    const int lane = tid & 63, wave = tid >> 6;
    const int wr = wave >> 1, wc = wave & 1;          // 2x2 waves, 64x64 each
    const int lrow = lane & 15, lkg = lane >> 4;

    // staging addressing: chunk c covers LDS bytes [c*1024, c*1024+1024)
    // lane covers LDS row c*8 + lane/8, slot lane&7 (16B slots, 8 per 128B row)
    // source slot pre-swizzled: gslot = slot ^ (row&7)
    const int srow  = (lane >> 3);                    // 0..7 within chunk
    const int gslot = (lane & 7) ^ srow;
    const int sxa   = lane & 7;                       // read-side XOR key (= lrow&7)

    f32x4 acc[4][4];
    const f32x4 z4 = {0.f, 0.f, 0.f, 0.f};
    #pragma unroll
    for (int a = 0; a < 4; ++a)
        #pragma unroll
        for (int b = 0; b < 4; ++b) acc[a][b] = z4;

    const size_t a_base = (size_t)brow * DM;
    const size_t b_base = (size_t)erow * DM;

    for (int kt = 0; kt < DM; kt += 64) {
        #pragma unroll
        for (int is = 0; is < 4; ++is) {
            int c = is * 4 + wave;                    // chunk 0..15
            int row = c * 8 + srow;
            size_t goff = (size_t)row * DM + kt + gslot * 8;
            gl_lds16(xb + a_base + goff, As + c * 512);
            gl_lds16(Wb + b_base + goff, Bs + c * 512);
        }
        __syncthreads();
        #pragma unroll
        for (int kk = 0; kk < 2; ++kk) {
            bf16x8 af[4], bfr[4];
            #pragma unroll
            for (int mi = 0; mi < 4; ++mi)
                af[mi] = *reinterpret_cast<const bf16x8*>(
                    &As[(wr*64 + mi*16 + lrow) * 64 + ((((kk<<2)|lkg) ^ sxa) << 3)]);
            #pragma unroll
            for (int ni = 0; ni < 4; ++ni)
                bfr[ni] = *reinterpret_cast<const bf16x8*>(
                    &Bs[(wc*64 + ni*16 + lrow) * 64 + ((((kk<<2)|lkg) ^ sxa) << 3)]);
            #pragma unroll
            for (int mi = 0; mi < 4; ++mi)
                #pragma unroll
                for (int ni = 0; ni < 4; ++ni)
                    acc[mi][ni] = __builtin_amdgcn_mfma_f32_16x16x32_bf16(
                        af[mi], bfr[ni], acc[mi][ni], 0, 0, 0);
        }
        __syncthreads();
    }

    // epilogue: re-layout through LDS.  T overlays As/Bs ([128][136] = 17408 ush)
    unsigned short* T = smem;
    if (sel == 0) {
        // T[m][n] = sigmoid(q); store natural [b,j,d]
        #pragma unroll
        for (int mi = 0; mi < 4; ++mi) {
            int m0 = wr*64 + mi*16 + lkg*4;
            #pragma unroll
            for (int ni = 0; ni < 4; ++ni) {
                int n = wc*64 + ni*16 + lrow;
                float bia = bias[ecol + n];
                #pragma unroll
                for (int r = 0; r < 4; ++r) {
                    float t = acc[mi][ni][r] + bia;
                    T[(m0 + r) * 136 + n] = f2b(1.f / (1.f + expf(-t)));
                }
            }
        }
        __syncthreads();
        #pragma unroll
        for (int it = 0; it < 8; ++it) {
            int idx = it * 256 + tid;
            int m = idx >> 4, ng = idx & 15;
            int4 vv = *reinterpret_cast<const int4*>(&T[m * 136 + ng * 8]);
            *reinterpret_cast<int4*>(&s_out[(size_t)(brow + m) * DM + ecol + ng * 8]) = vv;
        }
    } else {
        // T[n][m] = exp(k) or v; store transposed [b][d][j]
        const bool isk = (sel == 1);
        #pragma unroll
        for (int mi = 0; mi < 4; ++mi) {
            int m0 = wr*64 + mi*16 + lkg*4;
            #pragma unroll
            for (int ni = 0; ni < 4; ++ni) {
                int n = wc*64 + ni*16 + lrow;
                float bia = bias[ecol + n];
                union { unsigned short u[4]; uint2 p; } o;
                #pragma unroll
                for (int r = 0; r < 4; ++r) {
                    float t = acc[mi][ni][r] + bia;
                    o.u[r] = f2b(isk ? expf(t) : t);
                }
                *reinterpret_cast<uint2*>(&T[n * 136 + m0]) = o.p;
            }
        }
        __syncthreads();
        unsigned short* dst = isk ? ekT : vT;
        const size_t base = (size_t)(brow >> 10) * (DM * NSEQ);
        const int j0 = brow & (NSEQ - 1);
        #pragma unroll
        for (int it = 0; it < 8; ++it) {
            int idx = it * 256 + tid;
            int dr = idx >> 4, jg = idx & 15;
            int4 vv = *reinterpret_cast<const int4*>(&T[dr * 136 + jg * 8]);
            *reinterpret_cast<int4*>(&dst[base + (size_t)(ecol + dr) * NSEQ + j0 + jg * 8]) = vv;
        }
    }
}

// ---------------- P2: per-batch mixing GEMM + fused epilogue ----------------
// 4096 blocks, XCD-chunked: each XCD owns 8 contiguous batches.
// logical: batch (slow), d-tile (8), i-tile (8, fast)
__launch_bounds__(256)
__global__ void k_aft(const unsigned short* __restrict__ eb,
                      const unsigned short* __restrict__ ekT,
                      const unsigned short* __restrict__ ekvT,
                      const unsigned short* __restrict__ s_in,
                      float* __restrict__ out)
{
    __shared__ unsigned short smem[16384];            // 32 KiB: Aeb|Bek|Bev, swizzled
    unsigned short* Aeb = smem;                       // [128][64]
    unsigned short* Bek = smem + 128*64;              // [64][64]
    unsigned short* Bev = smem + 128*64 + 64*64;      // [64][64]

    const int bid = blockIdx.x;
    const int logical = (bid & 7) * 512 + (bid >> 3); // bijective: 4096 % 8 == 0
    const int b  = logical >> 6;
    const int i0 = (logical & 7) * 128;
    const int d0 = ((logical >> 3) & 7) * 64;

    const int tid = threadIdx.x;
    const int lane = tid & 63, wave = tid >> 6;
    const int wr = wave >> 1, wc = wave & 1;          // wave tile 64i x 32d
    const int lrow = lane & 15, lkg = lane >> 4;

    const int srow  = (lane >> 3);
    const int gslot = (lane & 7) ^ srow;
    const int sxa   = lane & 7;

    f32x4 accn[4][2], accd[4][2];
    const f32x4 z4 = {0.f, 0.f, 0.f, 0.f};
    #pragma unroll
    for (int a = 0; a < 4; ++a)
        #pragma unroll
        for (int c = 0; c < 2; ++c) { accn[a][c] = z4; accd[a][c] = z4; }

    const size_t bbase = (size_t)b * DM * NSEQ;

    for (int kt = 0; kt < NSEQ; kt += 64) {
        // 32 chunks: 0-15 A (eb 128x64), 16-23 Bek (64x64), 24-31 Bev (64x64)
        #pragma unroll
        for (int is = 0; is < 8; ++is) {
            int c = wave * 8 + is;
            if (c < 16) {
                int row = c * 8 + srow;
                gl_lds16(eb + (size_t)(i0 + row) * NSEQ + kt + gslot * 8,
                         Aeb + c * 512);
            } else if (c < 24) {
                int cc = c - 16, row = cc * 8 + srow;
                gl_lds16(ekT + bbase + (size_t)(d0 + row) * NSEQ + kt + gslot * 8,
                         Bek + cc * 512);
            } else {
                int cc = c - 24, row = cc * 8 + srow;
                gl_lds16(ekvT + bbase + (size_t)(d0 + row) * NSEQ + kt + gslot * 8,
                         Bev + cc * 512);
            }
        }
        __syncthreads();
        #pragma unroll
        for (int kk = 0; kk < 2; ++kk) {
            bf16x8 af[4];
            #pragma unroll
            for (int mi = 0; mi < 4; ++mi)
                af[mi] = *reinterpret_cast<const bf16x8*>(
                    &Aeb[(wr*64 + mi*16 + lrow) * 64 + ((((kk<<2)|lkg) ^ sxa) << 3)]);
            #pragma unroll
            for (int ni = 0; ni < 2; ++ni) {
                int c = (wc*32 + ni*16 + lrow) * 64 + ((((kk<<2)|lkg) ^ sxa) << 3);
                bf16x8 bk8 = *reinterpret_cast<const bf16x8*>(&Bek[c]);
                bf16x8 bv8 = *reinterpret_cast<const bf16x8*>(&Bev[c]);
                #pragma unroll
                for (int mi = 0; mi < 4; ++mi) {
                    accd[mi][ni] = __builtin_amdgcn_mfma_f32_16x16x32_bf16(
                        af[mi], bk8, accd[mi][ni], 0, 0, 0);
                    accn[mi][ni] = __builtin_amdgcn_mfma_f32_16x16x32_bf16(
                        af[mi], bv8, accn[mi][ni], 0, 0, 0);
                }
            }
        }
        __syncthreads();
    }

    // epilogue: out = sigmoid(q) * num / den
    #pragma unroll
    for (int mi = 0; mi < 4; ++mi) {
        int il = wr*64 + mi*16 + lkg*4;
        #pragma unroll
        for (int ni = 0; ni < 2; ++ni) {
            int dl = d0 + wc*32 + ni*16 + lrow;
            #pragma unroll
            for (int r = 0; r < 4; ++r) {
                size_t o = ((size_t)b * NSEQ + i0 + il + r) * DM + dl;
                float sv = b2f(s_in[o]);
                out[o] = sv * accn[mi][ni][r] / accd[mi][ni][r];
            }
        }
    }
}

extern "C" void kernel_launch(void* const* d_in, const int* in_sizes, int n_in,
                              void* d_out, int out_size, void* d_ws, size_t ws_size,
                              hipStream_t stream)
{
    const float* x  = (const float*)d_in[0];
    const float* Wq = (const float*)d_in[1];
    const float* bq = (const float*)d_in[2];
    const float* Wk = (const float*)d_in[3];
    const float* bk = (const float*)d_in[4];
    const float* Wv = (const float*)d_in[5];
    const float* bv = (const float*)d_in[6];
    const float* pb = (const float*)d_in[7];
    float* out = (float*)d_out;

    char* ws = (char*)d_ws;
    unsigned short* eb  = (unsigned short*)(ws);                          // 2 MiB
    unsigned short* Wb  = (unsigned short*)(ws + ((size_t)2   << 20));    // 1.5 MiB
    unsigned short* xb  = (unsigned short*)(ws + ((size_t)4   << 20));    // 64 MiB
    unsigned short* s   = (unsigned short*)(ws + ((size_t)68  << 20));    // 64 MiB
    unsigned short* ekT = (unsigned short*)(ws + ((size_t)132 << 20));    // 64 MiB
    unsigned short* vT  = (unsigned short*)(ws + ((size_t)196 << 20));    // 64 MiB -> ekvT

    k_eb <<<1024, 256, 0, stream>>>(pb, eb);
    k_cvt<<<16384, 256, 0, stream>>>(x,  xb);
    k_cvt<<<128,   256, 0, stream>>>(Wq, Wb);
    k_cvt<<<128,   256, 0, stream>>>(Wk, Wb + 512*512);
    k_cvt<<<128,   256, 0, stream>>>(Wv, Wb + 2*512*512);
    k_qkv<<<6144, 256, 0, stream>>>(xb, Wb, bq, bk, bv, s, ekT, vT);
    k_ekv<<<16384, 256, 0, stream>>>(ekT, vT);
    k_aft<<<dim3(4096), 256, 0, stream>>>(eb, ekT, vT, s, out);
}

// Round 4
// 388.725 us; speedup vs baseline: 1.2511x; 1.2511x over previous
//
#include <hip/hip_runtime.h>
#include <hip/hip_bf16.h>
#include <stdint.h>

// AFT-full, MI355X. Shapes: x[64,1024,512], W*[512,512], pos_bias[1024,1024].
//   q,k,v = x W^T + b ; out = sigmoid(q) * (eb@(e^k*v)) / (eb@e^k), eb=exp(pos_bias)
// Pipeline:
//   K0: eb = bf16(exp(pos_bias))  natural [i][j]
//   K1: xb = bf16(x); Wb[1536][512]: rows 0-511 Wq; rows 512+: Wk/Wv interleaved
//       in 64-row groups (group g: 64 Wk rows then 64 Wv rows for d in [g*64,g*64+64))
//   P1: fused QKV GEMM (bf16 MFMA, global_load_lds + slot-swizzle):
//        q-tiles  -> s = bf16(sigmoid(q)) natural [b,j,d]
//        kv-tiles -> Z rows: n = b*1024 + (d>>4)*32 + t*16 + (d&15)
//                    t=0: ekv = exp(k)*v ; t=1: ek = exp(k)   (K-major [n][j])
//   P2: ONE merged GEMM C[i,n] = eb @ Z^T : 256x256x64 tile, 8 waves, dbuf LDS,
//       4-phase pipelined (early gl_lds issue, raw barriers, setprio). num/den are
//       adjacent ni fragments -> register-local division epilogue, out fp32.
// Workspace: eb 2MiB@0, Wb 1.5MiB@2MiB, xb 64MiB@4MiB, s 64MiB@68MiB, Z 128MiB@132MiB.

#define NSEQ 1024
#define DM   512

typedef __attribute__((ext_vector_type(8))) short bf16x8;
typedef __attribute__((ext_vector_type(4))) float f32x4;

static __device__ __forceinline__ float b2f(unsigned short u) {
    union { uint32_t i; float f; } c; c.i = ((uint32_t)u) << 16; return c.f;
}
// round-to-nearest-even fp32 -> bf16 (inputs finite)
static __device__ __forceinline__ unsigned short f2b(float f) {
    union { float f; uint32_t i; } c; c.f = f;
    uint32_t r = c.i + 0x7FFFu + ((c.i >> 16) & 1u);
    return (unsigned short)(r >> 16);
}

// async global->LDS, 16B per lane; lds dest = wave-uniform base + lane*16
static __device__ __forceinline__ void gl_lds16(const unsigned short* g, unsigned short* l) {
    __builtin_amdgcn_global_load_lds(
        (const __attribute__((address_space(1))) unsigned int*)(g),
        (__attribute__((address_space(3))) unsigned int*)(l), 16, 0, 0);
}

__global__ void k_eb(const float* __restrict__ pb, unsigned short* __restrict__ eb) {
    int i = blockIdx.x * 256 + threadIdx.x;           // one float4 per thread
    float4 v = reinterpret_cast<const float4*>(pb)[i];
    union { unsigned short u[4]; uint2 p; } o;
    o.u[0] = f2b(expf(v.x)); o.u[1] = f2b(expf(v.y));
    o.u[2] = f2b(expf(v.z)); o.u[3] = f2b(expf(v.w));
    reinterpret_cast<uint2*>(eb)[i] = o.p;
}

// fp32 -> bf16, 8 elements/thread
__global__ void k_cvt(const float* __restrict__ src, unsigned short* __restrict__ dst) {
    int i = blockIdx.x * 256 + threadIdx.x;
    const float4* p = reinterpret_cast<const float4*>(src) + (size_t)i * 2;
    float4 f0 = p[0], f1 = p[1];
    union { unsigned short u[8]; int4 v; } o;
    o.u[0]=f2b(f0.x); o.u[1]=f2b(f0.y); o.u[2]=f2b(f0.z); o.u[3]=f2b(f0.w);
    o.u[4]=f2b(f1.x); o.u[5]=f2b(f1.y); o.u[6]=f2b(f1.z); o.u[7]=f2b(f1.w);
    reinterpret_cast<int4*>(dst)[i] = o.v;
}

// Wk/Wv rows into interleaved panel: W row r -> Wb[512 + (r>>6)*128 + toff + (r&63)]
__global__ void k_cvt_kv(const float* __restrict__ src, unsigned short* __restrict__ Wb,
                         int toff) {
    int i = blockIdx.x * 256 + threadIdx.x;           // 32768 threads, 8 elems each
    int r = i >> 6, c8 = i & 63;
    const float4* p = reinterpret_cast<const float4*>(src + (size_t)r * DM + c8 * 8);
    float4 f0 = p[0], f1 = p[1];
    union { unsigned short u[8]; int4 v; } o;
    o.u[0]=f2b(f0.x); o.u[1]=f2b(f0.y); o.u[2]=f2b(f0.z); o.u[3]=f2b(f0.w);
    o.u[4]=f2b(f1.x); o.u[5]=f2b(f1.y); o.u[6]=f2b(f1.z); o.u[7]=f2b(f1.w);
    int r2 = 512 + ((r >> 6) << 7) + toff + (r & 63);
    *reinterpret_cast<int4*>(&Wb[(size_t)r2 * DM + c8 * 8]) = o.v;
}

// ---------------- P1: fused QKV projection ----------------
// 6144 blocks: XCD-swizzled; etile (12) fast, mtile (512) slow.
// etile 0-3: q ; etile 4-11: kv group g = etile-4 (d in [g*64, g*64+64))
__launch_bounds__(256)
__global__ void k_qkv(const unsigned short* __restrict__ xb,
                      const unsigned short* __restrict__ Wb,
                      const float* __restrict__ bq, const float* __restrict__ bk,
                      const float* __restrict__ bv,
                      unsigned short* __restrict__ s_out,
                      unsigned short* __restrict__ Z)
{
    __shared__ unsigned short smem[17408];            // As|Bs (16384) ; T overlay (17408)
    unsigned short* As = smem;                        // [128][64] linear, slot-swizzled
    unsigned short* Bs = smem + 128 * 64;

    const int bid = blockIdx.x;
    const int swz = (bid & 7) * 768 + (bid >> 3);     // bijective: 6144 % 8 == 0
    const int mtile = swz / 12, etile = swz % 12;
    const int brow = mtile * 128;                     // global m (= b*1024 + j)
    const int erow = etile * 128;                     // row in Wb [1536][512]
    const bool isq = (etile < 4);
    const int g = etile - 4;                          // kv group (valid if !isq)

    const int tid = threadIdx.x;
    const int lane = tid & 63, wave = tid >> 6;
    const int wr = wave >> 1, wc = wave & 1;          // 2x2 waves, 64x64 each
    const int lrow = lane & 15, lkg = lane >> 4;

    const int srow  = (lane >> 3);                    // 0..7 within 8-row chunk
    const int gslot = (lane & 7) ^ srow;              // pre-swizzled source slot
    const int sxa   = lane & 7;                       // read-side XOR key

    f32x4 acc[4][4];
    const f32x4 z4 = {0.f, 0.f, 0.f, 0.f};
    #pragma unroll
    for (int a = 0; a < 4; ++a)
        #pragma unroll
        for (int b = 0; b < 4; ++b) acc[a][b] = z4;

    const size_t a_base = (size_t)brow * DM;
    const size_t b_base = (size_t)erow * DM;

    for (int kt = 0; kt < DM; kt += 64) {
        #pragma unroll
        for (int is = 0; is < 4; ++is) {
            int c = is * 4 + wave;                    // chunk 0..15
            int row = c * 8 + srow;
            size_t goff = (size_t)row * DM + kt + gslot * 8;
            gl_lds16(xb + a_base + goff, As + c * 512);
            gl_lds16(Wb + b_base + goff, Bs + c * 512);
        }
        __syncthreads();
        #pragma unroll
        for (int kk = 0; kk < 2; ++kk) {
            bf16x8 af[4], bfr[4];
            #pragma unroll
            for (int mi = 0; mi < 4; ++mi)
                af[mi] = *reinterpret_cast<const bf16x8*>(
                    &As[(wr*64 + mi*16 + lrow) * 64 + ((((kk<<2)|lkg) ^ sxa) << 3)]);
            #pragma unroll
            for (int ni = 0; ni < 4; ++ni)
                bfr[ni] = *reinterpret_cast<const bf16x8*>(
                    &Bs[(wc*64 + ni*16 + lrow) * 64 + ((((kk<<2)|lkg) ^ sxa) << 3)]);
            #pragma unroll
            for (int mi = 0; mi < 4; ++mi)
                #pragma unroll
                for (int ni = 0; ni < 4; ++ni)
                    acc[mi][ni] = __builtin_amdgcn_mfma_f32_16x16x32_bf16(
                        af[mi], bfr[ni], acc[mi][ni], 0, 0, 0);
        }
        __syncthreads();
    }

    // epilogue through LDS overlay T [128][136]
    unsigned short* T = smem;
    if (isq) {
        const int ecol = etile * 128;
        #pragma unroll
        for (int mi = 0; mi < 4; ++mi) {
            int m0 = wr*64 + mi*16 + lkg*4;
            #pragma unroll
            for (int ni = 0; ni < 4; ++ni) {
                int n = wc*64 + ni*16 + lrow;
                float bia = bq[ecol + n];
                #pragma unroll
                for (int r = 0; r < 4; ++r) {
                    float t = acc[mi][ni][r] + bia;
                    T[(m0 + r) * 136 + n] = f2b(1.f / (1.f + expf(-t)));
                }
            }
        }
        __syncthreads();
        #pragma unroll
        for (int it = 0; it < 8; ++it) {
            int idx = it * 256 + tid;
            int m = idx >> 4, ng = idx & 15;
            int4 vv = *reinterpret_cast<const int4*>(&T[m * 136 + ng * 8]);
            *reinterpret_cast<int4*>(&s_out[(size_t)(brow + m) * DM + ecol + ng * 8]) = vv;
        }
    } else {
        // T[n][m]: n<64 -> ek (exp applied), n>=64 -> v, both for d = g*64 + (n&63)
        #pragma unroll
        for (int mi = 0; mi < 4; ++mi) {
            int m0 = wr*64 + mi*16 + lkg*4;
            #pragma unroll
            for (int ni = 0; ni < 4; ++ni) {
                int n = wc*64 + ni*16 + lrow;
                int dd = g*64 + (n & 63);
                float bia = (n < 64) ? bk[dd] : bv[dd];
                union { unsigned short u[4]; uint2 p; } o;
                #pragma unroll
                for (int r = 0; r < 4; ++r) {
                    float t = acc[mi][ni][r] + bia;
                    o.u[r] = f2b((n < 64) ? expf(t) : t);
                }
                *reinterpret_cast<uint2*>(&T[n * 136 + m0]) = o.p;
            }
        }
        __syncthreads();
        // write Z rows: zr<64 -> ekv(d=g*64+zr) ; zr>=64 -> ek(d=g*64+zr-64)
        const int b = brow >> 10, j0 = brow & (NSEQ - 1);
        #pragma unroll
        for (int it = 0; it < 8; ++it) {
            int idx = it * 256 + tid;                 // 0..2047
            int zr = idx >> 4, jg = idx & 15;         // zr 0..127
            int dr = zr & 63;
            int d  = g * 64 + dr;
            union { unsigned short u[8]; int4 v; } o;
            if (zr < 64) {                            // ekv = ek * v
                union { unsigned short u[8]; int4 v; } pe, pv;
                pe.v = *reinterpret_cast<const int4*>(&T[dr * 136 + jg * 8]);
                pv.v = *reinterpret_cast<const int4*>(&T[(dr + 64) * 136 + jg * 8]);
                #pragma unroll
                for (int j = 0; j < 8; ++j) o.u[j] = f2b(b2f(pe.u[j]) * b2f(pv.u[j]));
            } else {                                  // ek copy
                o.v = *reinterpret_cast<const int4*>(&T[dr * 136 + jg * 8]);
            }
            int nn = ((d >> 4) << 5) + ((zr < 64) ? 0 : 16) + (d & 15);
            size_t off = ((size_t)(b * NSEQ + nn)) * NSEQ + j0 + jg * 8;
            *reinterpret_cast<int4*>(&Z[off]) = o.v;
        }
    }
}

// ---------------- P2: merged mixing GEMM, 256x256x64, 8 waves, pipelined ----
// C[i,n] = sum_j eb[i,j] * Z[n,j].  1024 blocks = 4 itiles x 256 ntiles,
// XCD-chunked, itile fastest (4 blocks share a B-panel -> same XCD L2).
__launch_bounds__(512)
__global__ void k_aft(const unsigned short* __restrict__ eb,
                      const unsigned short* __restrict__ Z,
                      const unsigned short* __restrict__ s_in,
                      float* __restrict__ out)
{
    extern __shared__ unsigned short smem[];          // 128 KiB
    // shorts: A0 @0, A1 @16384, B0 @32768, B1 @49152 ; each [256][64] swizzled

    const int bid = blockIdx.x;
    const int logical = (bid & 7) * 128 + (bid >> 3); // bijective: 1024 % 8 == 0
    const int itile = logical & 3, ntile = logical >> 2;
    const int i0 = itile * 256;
    const int n0 = ntile * 256;

    const int tid = threadIdx.x;
    const int lane = tid & 63, wave = tid >> 6;
    const int wr = wave >> 2, wq = wave & 3;          // 2x4 waves, 128x64 each
    const int lrow = lane & 15, lkg = lane >> 4;

    const int srow  = lane >> 3;
    const int gslot = (lane & 7) ^ srow;
    const int sxa   = lane & 7;

    f32x4 acc[8][4];
    const f32x4 z4 = {0.f, 0.f, 0.f, 0.f};
    #pragma unroll
    for (int a = 0; a < 8; ++a)
        #pragma unroll
        for (int c = 0; c < 4; ++c) acc[a][c] = z4;

    // prologue: stage tile 0 (A: eb rows i0.., B: Z rows n0..) into buf 0
    #pragma unroll
    for (int q = 0; q < 4; ++q) {
        int c = wave * 4 + q;                         // chunk 0..31 (8 rows each)
        int row = c * 8 + srow;
        gl_lds16(eb + (size_t)(i0 + row) * NSEQ + gslot * 8, smem + c * 512);
        gl_lds16(Z  + (size_t)(n0 + row) * NSEQ + gslot * 8, smem + 32768 + c * 512);
    }
    asm volatile("s_waitcnt vmcnt(0)" ::: "memory");
    __builtin_amdgcn_s_barrier();

    for (int t = 0; t < 16; ++t) {
        unsigned short* Ac = smem + (t & 1) * 16384;
        unsigned short* Bc = smem + 32768 + (t & 1) * 16384;
        unsigned short* An = smem + ((t + 1) & 1) * 16384;
        unsigned short* Bn = smem + 32768 + ((t + 1) & 1) * 16384;
        const int jn = (t + 1) * 64;                  // next tile K-offset
        const bool more = (t < 15);

        bf16x8 bfr[4];                                // B frags held across mi-halves
        #pragma unroll
        for (int p = 0; p < 4; ++p) {                 // (h,kk) = (0,0)(1,0)(0,1)(1,1)
            const int kk = p >> 1, h = p & 1;
            const int ko = (((kk << 2) | lkg) ^ sxa) << 3;
            if (h == 0) {                             // refresh B frags for this kk
                #pragma unroll
                for (int ni = 0; ni < 4; ++ni)
                    bfr[ni] = *reinterpret_cast<const bf16x8*>(
                        &Bc[(wq*64 + ni*16 + lrow) * 64 + ko]);
            }
            bf16x8 af[4];
            #pragma unroll
            for (int mi = 0; mi < 4; ++mi)
                af[mi] = *reinterpret_cast<const bf16x8*>(
                    &Ac[(wr*128 + (h*4 + mi)*16 + lrow) * 64 + ko]);
            // early-issue staging for tile t+1 (A in phase 0, B in phase 1)
            if (more && p == 0) {
                #pragma unroll
                for (int q = 0; q < 4; ++q) {
                    int c = wave * 4 + q;
                    gl_lds16(eb + (size_t)(i0 + c*8 + srow) * NSEQ + jn + gslot * 8,
                             An + c * 512);
                }
            }
            if (more && p == 1) {
                #pragma unroll
                for (int q = 0; q < 4; ++q) {
                    int c = wave * 4 + q;
                    gl_lds16(Z + (size_t)(n0 + c*8 + srow) * NSEQ + jn + gslot * 8,
                             Bn + c * 512);
                }
            }
            __builtin_amdgcn_s_setprio(1);
            #pragma unroll
            for (int mi = 0; mi < 4; ++mi)
                #pragma unroll
                for (int ni = 0; ni < 4; ++ni)
                    acc[h*4 + mi][ni] = __builtin_amdgcn_mfma_f32_16x16x32_bf16(
                        af[mi], bfr[ni], acc[h*4 + mi][ni], 0, 0, 0);
            __builtin_amdgcn_s_setprio(0);
            if (p == 3)                               // tile boundary: loads issued
                asm volatile("s_waitcnt vmcnt(0)" ::: "memory");  // >=2 phases ago
            __builtin_amdgcn_s_barrier();
        }
    }

    // epilogue: ni pairs (0,1) and (2,3) are (num, den) for the same d
    #pragma unroll
    for (int mi = 0; mi < 8; ++mi) {
        int i = i0 + wr*128 + mi*16 + lkg*4;
        #pragma unroll
        for (int pi = 0; pi < 2; ++pi) {
            int nA = n0 + wq*64 + pi*32 + lrow;       // t=0 (num) column
            int b  = nA >> 10, nn = nA & (NSEQ - 1);
            int d  = ((nn >> 5) << 4) + (nn & 15);
            #pragma unroll
            for (int r = 0; r < 4; ++r) {
                size_t o = ((size_t)(b * NSEQ + i + r)) * DM + d;
                float num = acc[mi][pi*2][r];
                float den = acc[mi][pi*2 + 1][r];
                out[o] = b2f(s_in[o]) * num / den;
            }
        }
    }
}

extern "C" void kernel_launch(void* const* d_in, const int* in_sizes, int n_in,
                              void* d_out, int out_size, void* d_ws, size_t ws_size,
                              hipStream_t stream)
{
    const float* x  = (const float*)d_in[0];
    const float* Wq = (const float*)d_in[1];
    const float* bq = (const float*)d_in[2];
    const float* Wk = (const float*)d_in[3];
    const float* bk = (const float*)d_in[4];
    const float* Wv = (const float*)d_in[5];
    const float* bv = (const float*)d_in[6];
    const float* pb = (const float*)d_in[7];
    float* out = (float*)d_out;

    char* ws = (char*)d_ws;
    unsigned short* eb  = (unsigned short*)(ws);                          // 2 MiB
    unsigned short* Wb  = (unsigned short*)(ws + ((size_t)2   << 20));    // 1.5 MiB
    unsigned short* xb  = (unsigned short*)(ws + ((size_t)4   << 20));    // 64 MiB
    unsigned short* s   = (unsigned short*)(ws + ((size_t)68  << 20));    // 64 MiB
    unsigned short* Z   = (unsigned short*)(ws + ((size_t)132 << 20));    // 128 MiB

    k_eb <<<1024, 256, 0, stream>>>(pb, eb);
    k_cvt<<<16384, 256, 0, stream>>>(x,  xb);
    k_cvt<<<128,   256, 0, stream>>>(Wq, Wb);
    k_cvt_kv<<<128, 256, 0, stream>>>(Wk, Wb, 0);
    k_cvt_kv<<<128, 256, 0, stream>>>(Wv, Wb, 64);
    k_qkv<<<6144, 256, 0, stream>>>(xb, Wb, bq, bk, bv, s, Z);
    k_aft<<<1024, 512, 131072, stream>>>(eb, Z, s, out);
}

// Round 5
// 343.270 us; speedup vs baseline: 1.4167x; 1.1324x over previous
//
#include <hip/hip_runtime.h>
#include <hip/hip_bf16.h>
#include <stdint.h>

// AFT-full, MI355X. Shapes: x[64,1024,512], W*[512,512], pos_bias[1024,1024].
//   q,k,v = x W^T + b ; out = sigmoid(q) * (eb@(e^k*v)) / (eb@e^k), eb=exp(pos_bias)
// Pipeline:
//   K0: eb = bf16(exp(pos_bias))  natural [i][j]
//   K1: xb = bf16(x); Wb[1536][512]: rows 0-511 Wq; rows 512+: Wk/Wv interleaved
//       in 64-row groups (group g: 64 Wk rows then 64 Wv rows for d in [g*64,g*64+64))
//   P1: fused QKV GEMM, 256x256x64 tile, 8 waves, dbuf LDS, 4-phase pipelined:
//        q-etiles  -> s = bf16(sigmoid(q)) natural [b,j,d]
//        kv-etiles -> Z rows: n = b*1024 + (d>>4)*32 + t*16 + (d&15)
//                     t=0: ekv = exp(k)*v ; t=1: ek = exp(k)   (K-major [n][j])
//       fast-math epilogue (__expf / rcp), 2-pass LDS transpose.
//   P2: ONE merged GEMM C[i,n] = eb @ Z^T : same 256x256x64 template. num/den are
//       adjacent ni fragments -> register-local division epilogue, out fp32.
// Workspace: eb 2MiB@0, Wb 1.5MiB@2MiB, xb 64MiB@4MiB, s 64MiB@68MiB, Z 128MiB@132MiB.

#define NSEQ 1024
#define DM   512

typedef __attribute__((ext_vector_type(8))) short bf16x8;
typedef __attribute__((ext_vector_type(4))) float f32x4;

static __device__ __forceinline__ float b2f(unsigned short u) {
    union { uint32_t i; float f; } c; c.i = ((uint32_t)u) << 16; return c.f;
}
// round-to-nearest-even fp32 -> bf16 (inputs finite)
static __device__ __forceinline__ unsigned short f2b(float f) {
    union { float f; uint32_t i; } c; c.f = f;
    uint32_t r = c.i + 0x7FFFu + ((c.i >> 16) & 1u);
    return (unsigned short)(r >> 16);
}

// async global->LDS, 16B per lane; lds dest = wave-uniform base + lane*16
static __device__ __forceinline__ void gl_lds16(const unsigned short* g, unsigned short* l) {
    __builtin_amdgcn_global_load_lds(
        (const __attribute__((address_space(1))) unsigned int*)(g),
        (__attribute__((address_space(3))) unsigned int*)(l), 16, 0, 0);
}

__global__ void k_eb(const float* __restrict__ pb, unsigned short* __restrict__ eb) {
    int i = blockIdx.x * 256 + threadIdx.x;           // one float4 per thread
    float4 v = reinterpret_cast<const float4*>(pb)[i];
    union { unsigned short u[4]; uint2 p; } o;
    o.u[0] = f2b(__expf(v.x)); o.u[1] = f2b(__expf(v.y));
    o.u[2] = f2b(__expf(v.z)); o.u[3] = f2b(__expf(v.w));
    reinterpret_cast<uint2*>(eb)[i] = o.p;
}

// fp32 -> bf16, 8 elements/thread
__global__ void k_cvt(const float* __restrict__ src, unsigned short* __restrict__ dst) {
    int i = blockIdx.x * 256 + threadIdx.x;
    const float4* p = reinterpret_cast<const float4*>(src) + (size_t)i * 2;
    float4 f0 = p[0], f1 = p[1];
    union { unsigned short u[8]; int4 v; } o;
    o.u[0]=f2b(f0.x); o.u[1]=f2b(f0.y); o.u[2]=f2b(f0.z); o.u[3]=f2b(f0.w);
    o.u[4]=f2b(f1.x); o.u[5]=f2b(f1.y); o.u[6]=f2b(f1.z); o.u[7]=f2b(f1.w);
    reinterpret_cast<int4*>(dst)[i] = o.v;
}

// Wk/Wv rows into interleaved panel: W row r -> Wb[512 + (r>>6)*128 + toff + (r&63)]
__global__ void k_cvt_kv(const float* __restrict__ src, unsigned short* __restrict__ Wb,
                         int toff) {
    int i = blockIdx.x * 256 + threadIdx.x;           // 32768 threads, 8 elems each
    int r = i >> 6, c8 = i & 63;
    const float4* p = reinterpret_cast<const float4*>(src + (size_t)r * DM + c8 * 8);
    float4 f0 = p[0], f1 = p[1];
    union { unsigned short u[8]; int4 v; } o;
    o.u[0]=f2b(f0.x); o.u[1]=f2b(f0.y); o.u[2]=f2b(f0.z); o.u[3]=f2b(f0.w);
    o.u[4]=f2b(f1.x); o.u[5]=f2b(f1.y); o.u[6]=f2b(f1.z); o.u[7]=f2b(f1.w);
    int r2 = 512 + ((r >> 6) << 7) + toff + (r & 63);
    *reinterpret_cast<int4*>(&Wb[(size_t)r2 * DM + c8 * 8]) = o.v;
}

// ---------------- P1: fused QKV projection, 256x256x64 pipelined ----------------
// 1536 blocks = 256 mtiles x 6 etiles; XCD-chunked, etile fastest.
// etile 0-1: q (cols etile*256..+256) ; etile 2-5: kv groups 2(e-2), 2(e-2)+1
__launch_bounds__(512)
__global__ void k_qkv(const unsigned short* __restrict__ xb,
                      const unsigned short* __restrict__ Wb,
                      const float* __restrict__ bq, const float* __restrict__ bk,
                      const float* __restrict__ bv,
                      unsigned short* __restrict__ s_out,
                      unsigned short* __restrict__ Z)
{
    extern __shared__ unsigned short smem[];          // 128 KiB
    // shorts: A0 @0, A1 @16384, B0 @32768, B1 @49152 ; each [256][64] swizzled

    const int bid = blockIdx.x;
    const int logical = (bid & 7) * 192 + (bid >> 3); // bijective: 1536 % 8 == 0
    const int mtile = logical / 6, etile = logical % 6;
    const int brow = mtile * 256;                     // global m (= b*1024 + j)
    const int erow = etile * 256;                     // row base in Wb [1536][512]
    const bool isq = (etile < 2);

    const int tid = threadIdx.x;
    const int lane = tid & 63, wave = tid >> 6;
    const int wr = wave >> 2, wq = wave & 3;          // 2x4 waves, 128m x 64e each
    const int lrow = lane & 15, lkg = lane >> 4;

    const int srow  = lane >> 3;
    const int gslot = (lane & 7) ^ srow;
    const int sxa   = lane & 7;

    f32x4 acc[8][4];
    const f32x4 z4 = {0.f, 0.f, 0.f, 0.f};
    #pragma unroll
    for (int a = 0; a < 8; ++a)
        #pragma unroll
        for (int c = 0; c < 4; ++c) acc[a][c] = z4;

    // prologue: stage tile 0
    #pragma unroll
    for (int q = 0; q < 4; ++q) {
        int c = wave * 4 + q;                         // chunk 0..31 (8 rows each)
        int row = c * 8 + srow;
        gl_lds16(xb + (size_t)(brow + row) * DM + gslot * 8, smem + c * 512);
        gl_lds16(Wb + (size_t)(erow + row) * DM + gslot * 8, smem + 32768 + c * 512);
    }
    asm volatile("s_waitcnt vmcnt(0)" ::: "memory");
    __builtin_amdgcn_s_barrier();

    for (int t = 0; t < 8; ++t) {
        unsigned short* Ac = smem + (t & 1) * 16384;
        unsigned short* Bc = smem + 32768 + (t & 1) * 16384;
        unsigned short* An = smem + ((t + 1) & 1) * 16384;
        unsigned short* Bn = smem + 32768 + ((t + 1) & 1) * 16384;
        const int jn = (t + 1) * 64;
        const bool more = (t < 7);

        bf16x8 bfr[4];
        #pragma unroll
        for (int p = 0; p < 4; ++p) {                 // (h,kk) = (0,0)(1,0)(0,1)(1,1)
            const int kk = p >> 1, h = p & 1;
            const int ko = (((kk << 2) | lkg) ^ sxa) << 3;
            if (h == 0) {
                #pragma unroll
                for (int ni = 0; ni < 4; ++ni)
                    bfr[ni] = *reinterpret_cast<const bf16x8*>(
                        &Bc[(wq*64 + ni*16 + lrow) * 64 + ko]);
            }
            bf16x8 af[4];
            #pragma unroll
            for (int mi = 0; mi < 4; ++mi)
                af[mi] = *reinterpret_cast<const bf16x8*>(
                    &Ac[(wr*128 + (h*4 + mi)*16 + lrow) * 64 + ko]);
            if (more && p == 0) {
                #pragma unroll
                for (int q = 0; q < 4; ++q) {
                    int c = wave * 4 + q;
                    gl_lds16(xb + (size_t)(brow + c*8 + srow) * DM + jn + gslot * 8,
                             An + c * 512);
                }
            }
            if (more && p == 1) {
                #pragma unroll
                for (int q = 0; q < 4; ++q) {
                    int c = wave * 4 + q;
                    gl_lds16(Wb + (size_t)(erow + c*8 + srow) * DM + jn + gslot * 8,
                             Bn + c * 512);
                }
            }
            __builtin_amdgcn_s_setprio(1);
            #pragma unroll
            for (int mi = 0; mi < 4; ++mi)
                #pragma unroll
                for (int ni = 0; ni < 4; ++ni)
                    acc[h*4 + mi][ni] = __builtin_amdgcn_mfma_f32_16x16x32_bf16(
                        af[mi], bfr[ni], acc[h*4 + mi][ni], 0, 0, 0);
            __builtin_amdgcn_s_setprio(0);
            if (p == 3)
                asm volatile("s_waitcnt vmcnt(0)" ::: "memory");
            __builtin_amdgcn_s_barrier();
        }
    }

    // epilogue through LDS overlay T (<=256*136 shorts = 69632 B), 2 passes
    unsigned short* T = smem;
    if (isq) {
        const int ecol = etile * 256;
        #pragma unroll
        for (int pp = 0; pp < 2; ++pp) {              // n-half [pp*128, pp*128+128)
            __syncthreads();
            if ((wq >> 1) == pp) {
                #pragma unroll
                for (int mi = 0; mi < 8; ++mi) {
                    int m0 = wr*128 + mi*16 + lkg*4;
                    #pragma unroll
                    for (int ni = 0; ni < 4; ++ni) {
                        int nl = (wq & 1) * 64 + ni*16 + lrow;   // 0..127
                        float bia = bq[ecol + pp*128 + nl];
                        #pragma unroll
                        for (int r = 0; r < 4; ++r) {
                            float tq = acc[mi][ni][r] + bia;
                            float sg = __builtin_amdgcn_rcpf(1.f + __expf(-tq));
                            T[(m0 + r) * 136 + nl] = f2b(sg);
                        }
                    }
                }
            }
            __syncthreads();
            #pragma unroll
            for (int it = 0; it < 8; ++it) {          // 256m x 128n copy
                int idx = it * 512 + tid;
                int m = idx >> 4, ng = idx & 15;
                int4 vv = *reinterpret_cast<const int4*>(&T[m * 136 + ng * 8]);
                *reinterpret_cast<int4*>(
                    &s_out[(size_t)(brow + m) * DM + ecol + pp*128 + ng * 8]) = vv;
            }
        }
    } else {
        // kv: T[n 256][m-half 128+pad]; n: [0,64)k g0, [64,128)v g0, [128,192)k g1,
        // [192,256)v g1 ; g0 = 2(etile-2), d = g*64 + (n&63)
        const int gbase = (etile - 2) * 2;
        const int b = brow >> 10;
        #pragma unroll
        for (int pp = 0; pp < 2; ++pp) {              // m-half [pp*128, pp*128+128)
            __syncthreads();
            if (wr == pp) {
                #pragma unroll
                for (int mi = 0; mi < 8; ++mi) {
                    int m0 = mi*16 + lkg*4;           // 0..127 (local m)
                    #pragma unroll
                    for (int ni = 0; ni < 4; ++ni) {
                        int n = wq*64 + ni*16 + lrow; // 0..255
                        int sub = (n >> 6) & 1, dr = n & 63;
                        int d = (gbase + (n >> 7)) * 64 + dr;
                        float bia = (sub == 0) ? bk[d] : bv[d];
                        union { unsigned short u[4]; uint2 p; } o;
                        #pragma unroll
                        for (int r = 0; r < 4; ++r) {
                            float tv = acc[mi][ni][r] + bia;
                            o.u[r] = f2b((sub == 0) ? __expf(tv) : tv);
                        }
                        *reinterpret_cast<uint2*>(&T[n * 136 + m0]) = o.p;
                    }
                }
            }
            __syncthreads();
            const int j0 = (brow & (NSEQ - 1)) + pp * 128;
            #pragma unroll
            for (int it = 0; it < 8; ++it) {          // 256 zr x 128 m copy
                int idx = it * 512 + tid;
                int zr = idx >> 4, jg = idx & 15;
                int gg = zr >> 7, sub2 = (zr >> 6) & 1, dr = zr & 63;
                int d = (gbase + gg) * 64 + dr;
                union { unsigned short u[8]; int4 v; } o;
                if (sub2 == 0) {                      // ekv = ek * v
                    union { unsigned short u[8]; int4 v; } pe, pv;
                    pe.v = *reinterpret_cast<const int4*>(&T[(gg*128 + dr) * 136 + jg*8]);
                    pv.v = *reinterpret_cast<const int4*>(&T[(gg*128 + 64 + dr) * 136 + jg*8]);
                    #pragma unroll
                    for (int j = 0; j < 8; ++j) o.u[j] = f2b(b2f(pe.u[j]) * b2f(pv.u[j]));
                } else {                              // ek copy
                    o.v = *reinterpret_cast<const int4*>(&T[(gg*128 + dr) * 136 + jg*8]);
                }
                int nn = ((d >> 4) << 5) + sub2 * 16 + (d & 15);
                size_t off = ((size_t)(b * NSEQ + nn)) * NSEQ + j0 + jg * 8;
                *reinterpret_cast<int4*>(&Z[off]) = o.v;
            }
        }
    }
}

// ---------------- P2: merged mixing GEMM, 256x256x64, 8 waves, pipelined ----
// C[i,n] = sum_j eb[i,j] * Z[n,j].  1024 blocks = 4 itiles x 256 ntiles,
// XCD-chunked, itile fastest (4 blocks share a B-panel -> same XCD L2).
__launch_bounds__(512)
__global__ void k_aft(const unsigned short* __restrict__ eb,
                      const unsigned short* __restrict__ Z,
                      const unsigned short* __restrict__ s_in,
                      float* __restrict__ out)
{
    extern __shared__ unsigned short smem[];          // 128 KiB
    // shorts: A0 @0, A1 @16384, B0 @32768, B1 @49152 ; each [256][64] swizzled

    const int bid = blockIdx.x;
    const int logical = (bid & 7) * 128 + (bid >> 3); // bijective: 1024 % 8 == 0
    const int itile = logical & 3, ntile = logical >> 2;
    const int i0 = itile * 256;
    const int n0 = ntile * 256;

    const int tid = threadIdx.x;
    const int lane = tid & 63, wave = tid >> 6;
    const int wr = wave >> 2, wq = wave & 3;          // 2x4 waves, 128x64 each
    const int lrow = lane & 15, lkg = lane >> 4;

    const int srow  = lane >> 3;
    const int gslot = (lane & 7) ^ srow;
    const int sxa   = lane & 7;

    f32x4 acc[8][4];
    const f32x4 z4 = {0.f, 0.f, 0.f, 0.f};
    #pragma unroll
    for (int a = 0; a < 8; ++a)
        #pragma unroll
        for (int c = 0; c < 4; ++c) acc[a][c] = z4;

    // prologue: stage tile 0 (A: eb rows i0.., B: Z rows n0..) into buf 0
    #pragma unroll
    for (int q = 0; q < 4; ++q) {
        int c = wave * 4 + q;                         // chunk 0..31 (8 rows each)
        int row = c * 8 + srow;
        gl_lds16(eb + (size_t)(i0 + row) * NSEQ + gslot * 8, smem + c * 512);
        gl_lds16(Z  + (size_t)(n0 + row) * NSEQ + gslot * 8, smem + 32768 + c * 512);
    }
    asm volatile("s_waitcnt vmcnt(0)" ::: "memory");
    __builtin_amdgcn_s_barrier();

    for (int t = 0; t < 16; ++t) {
        unsigned short* Ac = smem + (t & 1) * 16384;
        unsigned short* Bc = smem + 32768 + (t & 1) * 16384;
        unsigned short* An = smem + ((t + 1) & 1) * 16384;
        unsigned short* Bn = smem + 32768 + ((t + 1) & 1) * 16384;
        const int jn = (t + 1) * 64;                  // next tile K-offset
        const bool more = (t < 15);

        bf16x8 bfr[4];                                // B frags held across mi-halves
        #pragma unroll
        for (int p = 0; p < 4; ++p) {                 // (h,kk) = (0,0)(1,0)(0,1)(1,1)
            const int kk = p >> 1, h = p & 1;
            const int ko = (((kk << 2) | lkg) ^ sxa) << 3;
            if (h == 0) {                             // refresh B frags for this kk
                #pragma unroll
                for (int ni = 0; ni < 4; ++ni)
                    bfr[ni] = *reinterpret_cast<const bf16x8*>(
                        &Bc[(wq*64 + ni*16 + lrow) * 64 + ko]);
            }
            bf16x8 af[4];
            #pragma unroll
            for (int mi = 0; mi < 4; ++mi)
                af[mi] = *reinterpret_cast<const bf16x8*>(
                    &Ac[(wr*128 + (h*4 + mi)*16 + lrow) * 64 + ko]);
            // early-issue staging for tile t+1 (A in phase 0, B in phase 1)
            if (more && p == 0) {
                #pragma unroll
                for (int q = 0; q < 4; ++q) {
                    int c = wave * 4 + q;
                    gl_lds16(eb + (size_t)(i0 + c*8 + srow) * NSEQ + jn + gslot * 8,
                             An + c * 512);
                }
            }
            if (more && p == 1) {
                #pragma unroll
                for (int q = 0; q < 4; ++q) {
                    int c = wave * 4 + q;
                    gl_lds16(Z + (size_t)(n0 + c*8 + srow) * NSEQ + jn + gslot * 8,
                             Bn + c * 512);
                }
            }
            __builtin_amdgcn_s_setprio(1);
            #pragma unroll
            for (int mi = 0; mi < 4; ++mi)
                #pragma unroll
                for (int ni = 0; ni < 4; ++ni)
                    acc[h*4 + mi][ni] = __builtin_amdgcn_mfma_f32_16x16x32_bf16(
                        af[mi], bfr[ni], acc[h*4 + mi][ni], 0, 0, 0);
            __builtin_amdgcn_s_setprio(0);
            if (p == 3)                               // tile boundary: loads issued
                asm volatile("s_waitcnt vmcnt(0)" ::: "memory");  // >=2 phases ago
            __builtin_amdgcn_s_barrier();
        }
    }

    // epilogue: ni pairs (0,1) and (2,3) are (num, den) for the same d
    #pragma unroll
    for (int mi = 0; mi < 8; ++mi) {
        int i = i0 + wr*128 + mi*16 + lkg*4;
        #pragma unroll
        for (int pi = 0; pi < 2; ++pi) {
            int nA = n0 + wq*64 + pi*32 + lrow;       // t=0 (num) column
            int b  = nA >> 10, nn = nA & (NSEQ - 1);
            int d  = ((nn >> 5) << 4) + (nn & 15);
            #pragma unroll
            for (int r = 0; r < 4; ++r) {
                size_t o = ((size_t)(b * NSEQ + i + r)) * DM + d;
                float num = acc[mi][pi*2][r];
                float den = acc[mi][pi*2 + 1][r];
                out[o] = b2f(s_in[o]) * num / den;
            }
        }
    }
}

extern "C" void kernel_launch(void* const* d_in, const int* in_sizes, int n_in,
                              void* d_out, int out_size, void* d_ws, size_t ws_size,
                              hipStream_t stream)
{
    const float* x  = (const float*)d_in[0];
    const float* Wq = (const float*)d_in[1];
    const float* bq = (const float*)d_in[2];
    const float* Wk = (const float*)d_in[3];
    const float* bk = (const float*)d_in[4];
    const float* Wv = (const float*)d_in[5];
    const float* bv = (const float*)d_in[6];
    const float* pb = (const float*)d_in[7];
    float* out = (float*)d_out;

    char* ws = (char*)d_ws;
    unsigned short* eb  = (unsigned short*)(ws);                          // 2 MiB
    unsigned short* Wb  = (unsigned short*)(ws + ((size_t)2   << 20));    // 1.5 MiB
    unsigned short* xb  = (unsigned short*)(ws + ((size_t)4   << 20));    // 64 MiB
    unsigned short* s   = (unsigned short*)(ws + ((size_t)68  << 20));    // 64 MiB
    unsigned short* Z   = (unsigned short*)(ws + ((size_t)132 << 20));    // 128 MiB

    k_eb <<<1024, 256, 0, stream>>>(pb, eb);
    k_cvt<<<16384, 256, 0, stream>>>(x,  xb);
    k_cvt<<<128,   256, 0, stream>>>(Wq, Wb);
    k_cvt_kv<<<128, 256, 0, stream>>>(Wk, Wb, 0);
    k_cvt_kv<<<128, 256, 0, stream>>>(Wv, Wb, 64);
    k_qkv<<<1536, 512, 131072, stream>>>(xb, Wb, bq, bk, bv, s, Z);
    k_aft<<<1024, 512, 131072, stream>>>(eb, Z, s, out);
}